// Round 2
// baseline (954.611 us; speedup 1.0000x reference)
//
#include <hip/hip_runtime.h>
#include <cstdint>
#include <cstddef>

#define DI __device__ __forceinline__

typedef __bf16 bf16x8 __attribute__((ext_vector_type(8)));
typedef float  f32x4  __attribute__((ext_vector_type(4)));

constexpr int kB = 8, kS = 1024, kE = 1024, kH = 8, kD = 128;
constexpr int kM = kB * kS;           // 8192 rows total
constexpr float kSlope = 0.01f;       // leaky_relu negative slope

DI float bf2f(ushort u) { union { uint32_t i; float f; } v; v.i = ((uint32_t)u) << 16; return v.f; }
DI ushort f2bf(float f) {
    union { float f; uint32_t i; } v; v.f = f;
    return (ushort)((v.i + 0x7FFFu + ((v.i >> 16) & 1u)) >> 16);
}
// XOR swizzles on 16B slots (returns pre-shifted bits 4..6 / 4..5)
DI int swz3(int r) { return ((r ^ (r >> 3)) & 3) << 4; }
DI int swz7(int r) { return ((r ^ (r >> 3)) & 7) << 4; }

// load 8 elements as bf16x8 from bf16 (raw) or fp32 (convert RNE)
template<typename T> DI bf16x8 ld8(const T* p);
template<> DI bf16x8 ld8<ushort>(const ushort* p) { return *(const bf16x8*)p; }
template<> DI bf16x8 ld8<float>(const float* p) {
    const float4 f0 = *(const float4*)p;
    const float4 f1 = *(const float4*)(p + 4);
    union { bf16x8 v; ushort u[8]; } o;
    o.u[0] = f2bf(f0.x); o.u[1] = f2bf(f0.y); o.u[2] = f2bf(f0.z); o.u[3] = f2bf(f0.w);
    o.u[4] = f2bf(f1.x); o.u[5] = f2bf(f1.y); o.u[6] = f2bf(f1.z); o.u[7] = f2bf(f1.w);
    return o.v;
}
template<typename T> DI float ldf(const T* p);
template<> DI float ldf<ushort>(const ushort* p) { return bf2f(*p); }
template<> DI float ldf<float>(const float* p) { return *p; }

// ---------------------------------------------------------------------------
// GEMM: out[M,N] = epilogue(A[M,K] @ W[N,K]^T + bias)
// W is torch nn.Linear weight layout (out_features x in_features), fp32.
// 128x128 tile, BK=32, 4 waves (2x2), each wave 64x64 via 4x4 16x16x32 MFMAs.
// Reg-staged LDS (global->reg(+cvt)->LDS) with XOR slot swizzle; prefetch.
// ACT: 0 none, 1 leaky_relu. RESID: 0 none, 1 add residual (after ACT).
// TA: A dtype (float|ushort-bf16). TR: residual dtype. TO: output dtype.
// ---------------------------------------------------------------------------
template<int ACT, int RESID, typename TA, typename TR, typename TO>
__global__ __launch_bounds__(256)
void gemm_bt(const TA* __restrict__ A, const float* __restrict__ W,
             const float* __restrict__ bias, const TR* __restrict__ resb,
             TO* __restrict__ out, int M, int N, int K)
{
    __shared__ __align__(16) char At[128 * 64];   // 128 rows x 32 bf16 (64B)
    __shared__ __align__(16) char Wt[128 * 64];

    const int tid = threadIdx.x;
    const int l = tid & 63;
    const int wid = tid >> 6;
    const int wm = wid >> 1, wn = wid & 1;

    // XCD-aware bijective swizzle (grid % 8 == 0 here: 512 blocks)
    const int cpx = gridDim.x >> 3;
    const int sb = (blockIdx.x & 7) * cpx + (blockIdx.x >> 3);
    const int nbn = N >> 7;
    const int bm = sb / nbn, bn = sb - bm * nbn;
    const size_t row0 = (size_t)bm << 7;
    const size_t col0 = (size_t)bn << 7;

    // staging: slot s in [0,256) -> row s>>2, 8-elem chunk s&3 (two row-halves)
    const int r0 = tid >> 2, q0 = tid & 3;
    const int r1 = r0 + 64;
    const TA*    gA0 = A + (row0 + r0) * (size_t)K + q0 * 8;
    const TA*    gA1 = A + (row0 + r1) * (size_t)K + q0 * 8;
    const float* gW0 = W + (col0 + r0) * (size_t)K + q0 * 8;
    const float* gW1 = W + (col0 + r1) * (size_t)K + q0 * 8;
    const int wO0 = r0 * 64 + ((q0 << 4) ^ swz3(r0));
    const int wO1 = r1 * 64 + ((q0 << 4) ^ swz3(r1));

    f32x4 acc[4][4] = {};

    bf16x8 a0 = ld8(gA0);
    bf16x8 a1 = ld8(gA1);
    bf16x8 w0 = ld8(gW0);
    bf16x8 w1 = ld8(gW1);

    const int NT = K >> 5;
    for (int kt = 0; kt < NT; ++kt) {
        __syncthreads();                       // previous compute done
        *(bf16x8*)(At + wO0) = a0;
        *(bf16x8*)(At + wO1) = a1;
        *(bf16x8*)(Wt + wO0) = w0;
        *(bf16x8*)(Wt + wO1) = w1;
        __syncthreads();                       // staging visible
        if (kt + 1 < NT) {                     // prefetch next K-tile into regs
            const int ko = (kt + 1) << 5;
            a0 = ld8(gA0 + ko);
            a1 = ld8(gA1 + ko);
            w0 = ld8(gW0 + ko);
            w1 = ld8(gW1 + ko);
        }
        bf16x8 af[4], bfr[4];
        #pragma unroll
        for (int mi = 0; mi < 4; ++mi) {
            int r = (wm << 6) + (mi << 4) + (l & 15);
            af[mi] = *(const bf16x8*)(At + r * 64 + (((l >> 4) << 4) ^ swz3(r)));
        }
        #pragma unroll
        for (int ni = 0; ni < 4; ++ni) {
            int r = (wn << 6) + (ni << 4) + (l & 15);
            bfr[ni] = *(const bf16x8*)(Wt + r * 64 + (((l >> 4) << 4) ^ swz3(r)));
        }
        #pragma unroll
        for (int mi = 0; mi < 4; ++mi)
            #pragma unroll
            for (int ni = 0; ni < 4; ++ni)
                acc[mi][ni] = __builtin_amdgcn_mfma_f32_16x16x32_bf16(af[mi], bfr[ni], acc[mi][ni], 0, 0, 0);
    }

    // epilogue: C/D layout col=lane&15, row=(lane>>4)*4+reg (m89-verified)
    const int cr = (l >> 4) << 2;
    const int cc = l & 15;
    #pragma unroll
    for (int mi = 0; mi < 4; ++mi) {
        #pragma unroll
        for (int ni = 0; ni < 4; ++ni) {
            const size_t gr = row0 + (wm << 6) + (mi << 4) + cr;
            const size_t gc = col0 + (wn << 6) + (ni << 4) + cc;
            const float bv = bias[gc];
            #pragma unroll
            for (int r = 0; r < 4; ++r) {
                float v = acc[mi][ni][r] + bv;
                if (ACT) v = v > 0.f ? v : v * kSlope;
                const size_t off = (gr + r) * (size_t)N + gc;
                if (RESID) v += ldf(resb + off);
                if constexpr (sizeof(TO) == 4) out[off] = v;
                else                           out[off] = f2bf(v);
            }
        }
    }
}

// ---------------------------------------------------------------------------
// Flash attention forward. One block = (b, h, 64 q-rows); 4 waves x 16 q-rows.
// Q/K/V/QV/out all bf16 in (B*S, E) row-major with head column offset h*128.
// K staged row-major [64][128]bf16 (XOR-swz); V staged transposed Vt[d][t]
// so PV B-frags are contiguous ds_read_b128. P re-laid-out via per-wave LDS.
// ADD_QV: add qv (bf16) to output before store (FlowFace cross-attn).
// ---------------------------------------------------------------------------
template<int ADD_QV>
__global__ __launch_bounds__(256)
void attn_fwd(const ushort* __restrict__ Q, const ushort* __restrict__ K,
              const ushort* __restrict__ V, const ushort* __restrict__ QV,
              ushort* __restrict__ O, float scale)
{
    __shared__ __align__(16) char Kt[64 * 256];    // 16 KiB
    __shared__ __align__(16) char Vt[128 * 128];   // 16 KiB (transposed V)
    __shared__ __align__(16) char Pl[4][2048];     // per-wave 16x64 bf16

    const int tid = threadIdx.x;
    const int l = tid & 63, w = tid >> 6;

    const int cpx = gridDim.x >> 3;                 // 1024 blocks -> 128
    const int sb = (blockIdx.x & 7) * cpx + (blockIdx.x >> 3);
    const int qt = sb & 15;                         // q-tile within sequence
    const int bh = sb >> 4;
    const int h = bh & 7, b = bh >> 3;

    const size_t base = ((size_t)b << 10) * kE + ((size_t)h << 7);
    const size_t qrow0 = (size_t)(qt << 6) + (w << 4);   // row within batch

    // Q fragments (A-side: lane&15 = q-row, (lane>>4)*8 = k-offset)
    bf16x8 qf[4];
    #pragma unroll
    for (int kk = 0; kk < 4; ++kk)
        qf[kk] = *(const bf16x8*)(Q + base + (qrow0 + (l & 15)) * kE + (kk << 5) + ((l >> 4) << 3));

    f32x4 oacc[8] = {};
    float mrow[4] = {-1e30f, -1e30f, -1e30f, -1e30f};
    float lrow[4] = {0.f, 0.f, 0.f, 0.f};

    const int sr = tid >> 4, sc = tid & 15;   // staging: row group / 16B chunk

    for (int kt0 = 0; kt0 < 16; ++kt0) {
        __syncthreads();                      // previous tile's LDS reads done
        #pragma unroll
        for (int it = 0; it < 4; ++it) {
            const int r = sr + (it << 4);     // key row 0..63
            const size_t grow = base + (size_t)(kt0 * 64 + r) * kE + (sc << 3);
            uint4 kv = *(const uint4*)(K + grow);
            *(uint4*)(Kt + r * 256 + ((sc << 4) ^ swz7(r))) = kv;
            uint4 vv = *(const uint4*)(V + grow);
            const ushort* e = (const ushort*)&vv;
            #pragma unroll
            for (int j = 0; j < 8; ++j) {
                const int d = (sc << 3) + j;
                *(ushort*)(Vt + d * 128 + ((r * 2) ^ swz7(d))) = e[j];
            }
        }
        __syncthreads();

        // S = Q K^T  (lane holds S[q=(l>>4)*4+r][t=(l&15)+16*ni])
        f32x4 sacc[4] = {};
        #pragma unroll
        for (int ni = 0; ni < 4; ++ni) {
            const int r = (l & 15) + (ni << 4);
            #pragma unroll
            for (int kk = 0; kk < 4; ++kk) {
                bf16x8 kf = *(const bf16x8*)(Kt + r * 256 + ((((kk << 2) + (l >> 4)) << 4) ^ swz7(r)));
                sacc[ni] = __builtin_amdgcn_mfma_f32_16x16x32_bf16(qf[kk], kf, sacc[ni], 0, 0, 0);
            }
        }
        #pragma unroll
        for (int ni = 0; ni < 4; ++ni) sacc[ni] *= scale;

        // online softmax (rows reduced across the 16-lane subgroup)
        float corr[4];
        #pragma unroll
        for (int r = 0; r < 4; ++r) {
            float m0 = fmaxf(fmaxf(sacc[0][r], sacc[1][r]), fmaxf(sacc[2][r], sacc[3][r]));
            #pragma unroll
            for (int msk = 1; msk < 16; msk <<= 1) m0 = fmaxf(m0, __shfl_xor(m0, msk, 64));
            const float mn = fmaxf(mrow[r], m0);
            corr[r] = __expf(mrow[r] - mn);
            mrow[r] = mn;
        }
        float ps[4] = {0.f, 0.f, 0.f, 0.f};
        ushort pb[4][4];
        #pragma unroll
        for (int ni = 0; ni < 4; ++ni)
            #pragma unroll
            for (int r = 0; r < 4; ++r) {
                const float p = __expf(sacc[ni][r] - mrow[r]);
                ps[r] += p;
                pb[ni][r] = f2bf(p);
            }
        #pragma unroll
        for (int r = 0; r < 4; ++r) {
            float s = ps[r];
            #pragma unroll
            for (int msk = 1; msk < 16; msk <<= 1) s += __shfl_xor(s, msk, 64);
            lrow[r] = lrow[r] * corr[r] + s;
        }
        #pragma unroll
        for (int nd = 0; nd < 8; ++nd)
            #pragma unroll
            for (int r = 0; r < 4; ++r) oacc[nd][r] *= corr[r];

        // P -> per-wave LDS (re-layout to A-fragment), then PV
        char* pw = Pl[w];
        #pragma unroll
        for (int ni = 0; ni < 4; ++ni)
            #pragma unroll
            for (int r = 0; r < 4; ++r) {
                const int q = ((l >> 4) << 2) + r;
                const int t = (l & 15) + (ni << 4);
                *(ushort*)(pw + q * 128 + ((t * 2) ^ swz7(q))) = pb[ni][r];
            }
        #pragma unroll
        for (int tg = 0; tg < 2; ++tg) {
            const int q = l & 15;
            bf16x8 pf = *(const bf16x8*)(pw + q * 128 + ((((tg << 2) + (l >> 4)) << 4) ^ swz7(q)));
            #pragma unroll
            for (int nd = 0; nd < 8; ++nd) {
                const int d = (l & 15) + (nd << 4);
                bf16x8 vf = *(const bf16x8*)(Vt + d * 128 + ((((tg << 2) + (l >> 4)) << 4) ^ swz7(d)));
                oacc[nd] = __builtin_amdgcn_mfma_f32_16x16x32_bf16(pf, vf, oacc[nd], 0, 0, 0);
            }
        }
    }

    // epilogue: O /= l  (+ qv), bf16 store
    const size_t orow = qrow0 + ((l >> 4) << 2);
    #pragma unroll
    for (int r = 0; r < 4; ++r) {
        const float inv = 1.f / lrow[r];
        const size_t ro = base + (orow + r) * kE;
        #pragma unroll
        for (int nd = 0; nd < 8; ++nd) {
            const size_t c = (l & 15) + (nd << 4);
            float v = oacc[nd][r] * inv;
            if (ADD_QV) v += bf2f(QV[ro + c]);
            O[ro + c] = f2bf(v);
        }
    }
}

// ---------------------------------------------------------------------------
// LayerNorm over the last two dims (S,E) per batch, on bf16 h1.
// ---------------------------------------------------------------------------
__global__ void ln_partial(const ushort* __restrict__ h1, float2* __restrict__ part)
{
    __shared__ float sa[8];
    const int blk = blockIdx.x;                     // 256 = 8 batches x 32 chunks
    const size_t off = ((size_t)blk) << 15;         // 32768 elements per chunk
    float s = 0.f, s2 = 0.f;
    for (int i = threadIdx.x; i < 4096; i += 256) {
        uint4 u = *(const uint4*)(h1 + off + (size_t)i * 8);
        const ushort* e = (const ushort*)&u;
        #pragma unroll
        for (int j = 0; j < 8; ++j) { const float v = bf2f(e[j]); s += v; s2 += v * v; }
    }
    #pragma unroll
    for (int m = 1; m < 64; m <<= 1) { s += __shfl_xor(s, m, 64); s2 += __shfl_xor(s2, m, 64); }
    const int w = threadIdx.x >> 6;
    if ((threadIdx.x & 63) == 0) { sa[w * 2] = s; sa[w * 2 + 1] = s2; }
    __syncthreads();
    if (threadIdx.x == 0)
        part[blk] = make_float2(sa[0] + sa[2] + sa[4] + sa[6], sa[1] + sa[3] + sa[5] + sa[7]);
}

__global__ void ln_finish(const float2* __restrict__ part, float2* __restrict__ stats)
{
    const int b = threadIdx.x;
    if (b < 8) {
        float s = 0.f, s2 = 0.f;
        for (int c = 0; c < 32; ++c) { const float2 v = part[b * 32 + c]; s += v.x; s2 += v.y; }
        const float mu = s * (1.f / 1048576.f);
        const float var = s2 * (1.f / 1048576.f) - mu * mu;
        stats[b] = make_float2(mu, rsqrtf(var + 1e-5f));
    }
}

__global__ void ln_apply(const ushort* __restrict__ h1, const float2* __restrict__ stats,
                         const float* __restrict__ gw, const float* __restrict__ gb,
                         ushort* __restrict__ hn)
{
    const size_t i = ((size_t)blockIdx.x * 256 + threadIdx.x) * 8;
    const int b = (int)(i >> 20);
    const size_t r = i & 1048575;                   // index within (S,E)
    const float2 st = stats[b];
    uint4 uv = *(const uint4*)(h1 + i);
    const float4 w0 = *(const float4*)(gw + r);
    const float4 w1 = *(const float4*)(gw + r + 4);
    const float4 b0 = *(const float4*)(gb + r);
    const float4 b1 = *(const float4*)(gb + r + 4);
    const float wv[8] = {w0.x, w0.y, w0.z, w0.w, w1.x, w1.y, w1.z, w1.w};
    const float bv[8] = {b0.x, b0.y, b0.z, b0.w, b1.x, b1.y, b1.z, b1.w};
    const ushort* ev = (const ushort*)&uv;
    ushort o[8];
    #pragma unroll
    for (int j = 0; j < 8; ++j)
        o[j] = f2bf((bf2f(ev[j]) - st.x) * st.y * wv[j] + bv[j]);
    *(uint4*)(hn + i) = *(const uint4*)o;
}

// ---------------------------------------------------------------------------
extern "C" void kernel_launch(void* const* d_in, const int* in_sizes, int n_in,
                              void* d_out, int out_size, void* d_ws, size_t ws_size,
                              hipStream_t stream)
{
    (void)in_sizes; (void)n_in; (void)out_size; (void)ws_size;
    const float* X = (const float*)d_in[0];
    const float* Y = (const float*)d_in[1];
    auto P = [&](int i) { return (const float*)d_in[i]; };

    char* ws = (char*)d_ws;
    const size_t SZ = (size_t)kM * kE * 2;          // 16 MiB per bf16 buffer
    ushort* B0 = (ushort*)(ws);
    ushort* B1 = (ushort*)(ws + SZ);
    ushort* B2 = (ushort*)(ws + 2 * SZ);
    ushort* B3 = (ushort*)(ws + 3 * SZ);
    ushort* B4 = (ushort*)(ws + 4 * SZ);
    ushort* B5 = (ushort*)(ws + 5 * SZ);
    float2* PART = (float2*)(ws + 6 * SZ);
    float2* STATS = PART + 256;

    const dim3 blk(256);
    const dim3 gg(512);        // GEMM: (8192/128)*(1024/128)
    const dim3 ga(1024);       // attn: 8*8*16
    const float SA_SCALE = 0.08838834764831845f;   // 1/sqrt(128)

    // --- cross attention ---
    gemm_bt<0,0><<<gg, blk, 0, stream>>>(X, P(2),  P(3),  (const ushort*)nullptr, B0, kM, kE, kE);  // q
    gemm_bt<0,0><<<gg, blk, 0, stream>>>(X, P(4),  P(5),  (const ushort*)nullptr, B1, kM, kE, kE);  // qv
    gemm_bt<0,0><<<gg, blk, 0, stream>>>(Y, P(6),  P(7),  (const ushort*)nullptr, B2, kM, kE, kE);  // k
    gemm_bt<0,0><<<gg, blk, 0, stream>>>(Y, P(8),  P(9),  (const ushort*)nullptr, B3, kM, kE, kE);  // kv
    attn_fwd<1><<<ga, blk, 0, stream>>>(B0, B2, B3, B1, B4, 1.0f);                   // softmax(qk^T)kv + qv
    gemm_bt<0,1><<<gg, blk, 0, stream>>>(B4, P(10), P(11), X, B5, kM, kE, kE);       // h1 = x + ca

    // --- LayerNorm over (S,E) per batch ---
    ln_partial<<<dim3(256), blk, 0, stream>>>(B5, PART);
    ln_finish<<<dim3(1), dim3(64), 0, stream>>>(PART, STATS);
    ln_apply<<<dim3(4096), blk, 0, stream>>>(B5, STATS, P(12), P(13), B0);           // hn

    // --- FeedForward (leaky_relu x3) + residual ---
    gemm_bt<1,0><<<gg, blk, 0, stream>>>(B0, P(14), P(15), (const ushort*)nullptr, B1, kM, kE, kE); // f1
    gemm_bt<1,0><<<gg, blk, 0, stream>>>(B1, P(16), P(17), (const ushort*)nullptr, B2, kM, kE, kE); // f2
    gemm_bt<1,1><<<gg, blk, 0, stream>>>(B2, P(18), P(19), B0, B3, kM, kE, kE);      // h2 = hn + lr(f3)

    // --- self attention 1 ---
    gemm_bt<0,0><<<gg, blk, 0, stream>>>(B3, P(20), P(21), (const ushort*)nullptr, B0, kM, kE, kE); // q1
    gemm_bt<0,0><<<gg, blk, 0, stream>>>(B3, P(22), P(23), (const ushort*)nullptr, B1, kM, kE, kE); // k1
    gemm_bt<0,0><<<gg, blk, 0, stream>>>(B3, P(24), P(25), (const ushort*)nullptr, B2, kM, kE, kE); // v1
    attn_fwd<0><<<ga, blk, 0, stream>>>(B0, B1, B2, nullptr, B4, SA_SCALE);
    gemm_bt<0,0><<<gg, blk, 0, stream>>>(B4, P(26), P(27), (const ushort*)nullptr, B5, kM, kE, kE); // h3

    // --- self attention 2 ---
    gemm_bt<0,0><<<gg, blk, 0, stream>>>(B5, P(28), P(29), (const ushort*)nullptr, B0, kM, kE, kE); // q2
    gemm_bt<0,0><<<gg, blk, 0, stream>>>(B5, P(30), P(31), (const ushort*)nullptr, B1, kM, kE, kE); // k2
    gemm_bt<0,0><<<gg, blk, 0, stream>>>(B5, P(32), P(33), (const ushort*)nullptr, B2, kM, kE, kE); // v2
    attn_fwd<0><<<ga, blk, 0, stream>>>(B0, B1, B2, nullptr, B3, SA_SCALE);
    gemm_bt<0,0><<<gg, blk, 0, stream>>>(B3, P(34), P(35), (const ushort*)nullptr, (float*)d_out, kM, kE, kE);
}

// Round 4
// 798.777 us; speedup vs baseline: 1.1951x; 1.1951x over previous
//
#include <hip/hip_runtime.h>
#include <cstdint>
#include <cstddef>

#define DI __device__ __forceinline__

typedef __bf16 bf16x8 __attribute__((ext_vector_type(8)));
typedef float  f32x4  __attribute__((ext_vector_type(4)));

constexpr int kE = 1024;
constexpr int kM = 8192;
constexpr float kSlope = 0.01f;

DI float bf2f(ushort u) { union { uint32_t i; float f; } v; v.i = ((uint32_t)u) << 16; return v.f; }
DI ushort f2bf(float f) {
    union { float f; uint32_t i; } v; v.f = f;
    return (ushort)((v.i + 0x7FFFu + ((v.i >> 16) & 1u)) >> 16);
}
DI bf16x8 ld8f(const float* p) {
    const float4 f0 = *(const float4*)p;
    const float4 f1 = *(const float4*)(p + 4);
    union { bf16x8 v; ushort u[8]; } o;
    o.u[0] = f2bf(f0.x); o.u[1] = f2bf(f0.y); o.u[2] = f2bf(f0.z); o.u[3] = f2bf(f0.w);
    o.u[4] = f2bf(f1.x); o.u[5] = f2bf(f1.y); o.u[6] = f2bf(f1.z); o.u[7] = f2bf(f1.w);
    return o.v;
}
template<typename T> DI float ldf(const T* p);
template<> DI float ldf<ushort>(const ushort* p) { return bf2f(*p); }
template<> DI float ldf<float>(const float* p) { return *p; }

DI void gload16(const void* g, void* lds) {
    __builtin_amdgcn_global_load_lds((const __attribute__((address_space(1))) void*)g,
                                     (__attribute__((address_space(3))) void*)lds, 16, 0, 0);
}

// XOR swizzle helper (16B-slot granularity on bits 4..6)
DI int swz7(int r) { return ((r ^ (r >> 3)) & 7) << 4; }

// ---------------------------------------------------------------------------
// cvt_pack: fp32 weights -> packed bf16 WB; x,y -> bf16; biases -> packed fp32
// ---------------------------------------------------------------------------
struct PtrTab { const float* w[16]; const float* b[16]; const float* x; const float* y; };

__global__ __launch_bounds__(256)
void cvt_pack(PtrTab t, ushort* __restrict__ WB, ushort* __restrict__ Xb,
              ushort* __restrict__ Yb, float* __restrict__ BP)
{
    const int blk = blockIdx.x, tid = threadIdx.x;
    if (blk < 16384) {
        const float* src; ushort* dst; size_t idx;
        if (blk < 8192)       { const int w = blk >> 9; idx = (size_t)(blk & 511) * 2048 + tid * 8; src = t.w[w]; dst = WB + (size_t)w * 1048576; }
        else if (blk < 12288) { idx = (size_t)(blk - 8192) * 2048 + tid * 8;  src = t.x; dst = Xb; }
        else                  { idx = (size_t)(blk - 12288) * 2048 + tid * 8; src = t.y; dst = Yb; }
        *(bf16x8*)(dst + idx) = ld8f(src + idx);
    } else {
        const size_t i = (size_t)(blk - 16384) * 2048 + tid * 8;
        const int w = (int)(i >> 10), off = (int)(i & 1023);
        *(float4*)(BP + i)     = *(const float4*)(t.b[w] + off);
        *(float4*)(BP + i + 4) = *(const float4*)(t.b[w] + off + 4);
    }
}

// ---------------------------------------------------------------------------
// bf16 GEMM: out[8192,N] = epi(A[8192,1024] @ W[N,1024]^T + bias)
// 128x128 tile, BK=32, 4 waves(2x2), global_load_lds dwordx4 staging,
// double-buffered, 1 barrier/iter. Swizzle: LDS slot s holds global chunk
// c = s ^ ((r>>1)&3); frag read slot = (l>>4) ^ ((r>>1)&3).
// ---------------------------------------------------------------------------
template<int ACT, int RESID, typename TR, typename TO>
__global__ __launch_bounds__(256)
void gemm_bf16(const ushort* __restrict__ A, const ushort* __restrict__ W,
               const float* __restrict__ bias, const TR* __restrict__ resb,
               TO* __restrict__ out, int N)
{
    __shared__ __align__(16) char sm[2][16384];   // [buf][A 8K | W 8K]
    constexpr int K = 1024;
    const int tid = threadIdx.x, l = tid & 63, wid = tid >> 6;
    const int wm = wid >> 1, wn = wid & 1;

    const int cpx = gridDim.x >> 3;
    const int sb = (blockIdx.x & 7) * cpx + (blockIdx.x >> 3);
    const int nbn = N >> 7;
    const int bm = sb / nbn, bn = sb - bm * nbn;
    const size_t row0 = (size_t)bm << 7, col0 = (size_t)bn << 7;

    // staging source precompute: o = (wid*2+i)*1024 + l*16
    const int o0 = (wid * 2) * 1024 + (l << 4), o1 = o0 + 1024;
    const int r0s = o0 >> 6, c0s = ((o0 >> 4) & 3) ^ ((r0s >> 1) & 3);
    const int r1s = o1 >> 6, c1s = ((o1 >> 4) & 3) ^ ((r1s >> 1) & 3);
    const ushort* gA0 = A + (row0 + r0s) * K + c0s * 8;
    const ushort* gA1 = A + (row0 + r1s) * K + c1s * 8;
    const ushort* gW0 = W + (col0 + r0s) * K + c0s * 8;
    const ushort* gW1 = W + (col0 + r1s) * K + c1s * 8;
    const int d0 = (wid * 2) * 1024, d1 = d0 + 1024;

    f32x4 acc[4][4] = {};

    { // prologue: stage tile 0
        gload16(gA0, sm[0] + d0); gload16(gA1, sm[0] + d1);
        gload16(gW0, sm[0] + 8192 + d0); gload16(gW1, sm[0] + 8192 + d1);
    }
    __syncthreads();

    for (int kt = 0; kt < 32; ++kt) {
        const int cur = kt & 1;
        if (kt + 1 < 32) {
            const int ko = (kt + 1) << 5;
            char* nb = sm[cur ^ 1];
            gload16(gA0 + ko, nb + d0); gload16(gA1 + ko, nb + d1);
            gload16(gW0 + ko, nb + 8192 + d0); gload16(gW1 + ko, nb + 8192 + d1);
        }
        const char* At = sm[cur];
        const char* Wt = sm[cur] + 8192;
        bf16x8 af[4], bfr[4];
        #pragma unroll
        for (int mi = 0; mi < 4; ++mi) {
            const int r = (wm << 6) + (mi << 4) + (l & 15);
            af[mi] = *(const bf16x8*)(At + r * 64 + ((((l >> 4) ^ ((r >> 1) & 3))) << 4));
        }
        #pragma unroll
        for (int ni = 0; ni < 4; ++ni) {
            const int r = (wn << 6) + (ni << 4) + (l & 15);
            bfr[ni] = *(const bf16x8*)(Wt + r * 64 + ((((l >> 4) ^ ((r >> 1) & 3))) << 4));
        }
        #pragma unroll
        for (int mi = 0; mi < 4; ++mi)
            #pragma unroll
            for (int ni = 0; ni < 4; ++ni)
                acc[mi][ni] = __builtin_amdgcn_mfma_f32_16x16x32_bf16(af[mi], bfr[ni], acc[mi][ni], 0, 0, 0);
        __syncthreads();
    }

    // epilogue: C/D layout col=lane&15, row=(lane>>4)*4+reg
    const int cr = (l >> 4) << 2, cc = l & 15;
    #pragma unroll
    for (int mi = 0; mi < 4; ++mi) {
        #pragma unroll
        for (int ni = 0; ni < 4; ++ni) {
            const size_t gr = row0 + (wm << 6) + (mi << 4) + cr;
            const size_t gc = col0 + (wn << 6) + (ni << 4) + cc;
            const float bv = bias[gc];
            #pragma unroll
            for (int r = 0; r < 4; ++r) {
                float v = acc[mi][ni][r] + bv;
                if (ACT) v = v > 0.f ? v : v * kSlope;
                const size_t off = (gr + r) * (size_t)N + gc;
                if (RESID) v += ldf(resb + off);
                if constexpr (sizeof(TO) == 4) out[off] = v;
                else                           out[off] = f2bf(v);
            }
        }
    }
}

// ---------------------------------------------------------------------------
// Flash attention (round-2 verified structure, ported to strided inputs).
// One block = (b, h, 64 q-rows); 4 waves x 16 q-rows. Inputs bf16 with row
// stride ld (packed projections); output stride 1024.
// K staged row-major [64][128]bf16 (XOR-swz) via reg->LDS uint4 stores;
// V staged transposed Vt[d][t] via scalar stores. P via per-wave LDS.
// ADD_QV: add qv (bf16, stride ld) before store.
// ---------------------------------------------------------------------------
template<int ADD_QV>
__global__ __launch_bounds__(256)
void attn_fwd(const ushort* __restrict__ Q, const ushort* __restrict__ K,
              const ushort* __restrict__ V, const ushort* __restrict__ QV,
              ushort* __restrict__ O, int ld, float scale)
{
    __shared__ __align__(16) char Kt[64 * 256];    // 16 KiB
    __shared__ __align__(16) char Vt[128 * 128];   // 16 KiB (transposed V)
    __shared__ __align__(16) char Pl[4][2048];     // per-wave 16x64 bf16

    const int tid = threadIdx.x;
    const int l = tid & 63, w = tid >> 6;

    const int cpx = gridDim.x >> 3;                 // 1024 blocks -> 128
    const int sb = (blockIdx.x & 7) * cpx + (blockIdx.x >> 3);
    const int qt = sb & 15;
    const int bh = sb >> 4;
    const int h = bh & 7, b = bh >> 3;

    const size_t bi = ((size_t)b << 10) * (size_t)ld + ((size_t)h << 7);
    const size_t bo = ((size_t)b << 10) * 1024 + ((size_t)h << 7);
    const size_t qrow0 = (size_t)(qt << 6) + (w << 4);

    // Q fragments (A-side: lane&15 = q-row, (lane>>4)*8 = k-offset)
    bf16x8 qf[4];
    #pragma unroll
    for (int kk = 0; kk < 4; ++kk)
        qf[kk] = *(const bf16x8*)(Q + bi + (qrow0 + (l & 15)) * ld + (kk << 5) + ((l >> 4) << 3));

    f32x4 oacc[8] = {};
    float mrow[4] = {-1e30f, -1e30f, -1e30f, -1e30f};
    float lrow[4] = {0.f, 0.f, 0.f, 0.f};

    const int sr = tid >> 4, sc = tid & 15;   // staging: row group / 16B chunk

    for (int kt0 = 0; kt0 < 16; ++kt0) {
        __syncthreads();                      // previous tile's LDS reads done
        #pragma unroll
        for (int it = 0; it < 4; ++it) {
            const int r = sr + (it << 4);     // key row 0..63
            const size_t grow = bi + (size_t)(kt0 * 64 + r) * ld + (sc << 3);
            uint4 kv = *(const uint4*)(K + grow);
            *(uint4*)(Kt + r * 256 + ((sc << 4) ^ swz7(r))) = kv;
            uint4 vv = *(const uint4*)(V + grow);
            const ushort* e = (const ushort*)&vv;
            #pragma unroll
            for (int j = 0; j < 8; ++j) {
                const int d = (sc << 3) + j;
                *(ushort*)(Vt + d * 128 + ((r * 2) ^ swz7(d))) = e[j];
            }
        }
        __syncthreads();

        // S = Q K^T  (lane holds S[q=(l>>4)*4+r][t=(l&15)+16*ni])
        f32x4 sacc[4] = {};
        #pragma unroll
        for (int ni = 0; ni < 4; ++ni) {
            const int r = (l & 15) + (ni << 4);
            #pragma unroll
            for (int kk = 0; kk < 4; ++kk) {
                bf16x8 kf = *(const bf16x8*)(Kt + r * 256 + ((((kk << 2) + (l >> 4)) << 4) ^ swz7(r)));
                sacc[ni] = __builtin_amdgcn_mfma_f32_16x16x32_bf16(qf[kk], kf, sacc[ni], 0, 0, 0);
            }
        }
        #pragma unroll
        for (int ni = 0; ni < 4; ++ni) sacc[ni] *= scale;

        // online softmax (rows reduced across the 16-lane subgroup)
        float corr[4];
        #pragma unroll
        for (int r = 0; r < 4; ++r) {
            float m0 = fmaxf(fmaxf(sacc[0][r], sacc[1][r]), fmaxf(sacc[2][r], sacc[3][r]));
            #pragma unroll
            for (int m = 1; m < 16; m <<= 1) m0 = fmaxf(m0, __shfl_xor(m0, m, 64));
            const float mn = fmaxf(mrow[r], m0);
            corr[r] = __expf(mrow[r] - mn);
            mrow[r] = mn;
        }
        float ps[4] = {0.f, 0.f, 0.f, 0.f};
        ushort pb[4][4];
        #pragma unroll
        for (int ni = 0; ni < 4; ++ni)
            #pragma unroll
            for (int r = 0; r < 4; ++r) {
                const float p = __expf(sacc[ni][r] - mrow[r]);
                ps[r] += p;
                pb[ni][r] = f2bf(p);
            }
        #pragma unroll
        for (int r = 0; r < 4; ++r) {
            float s = ps[r];
            #pragma unroll
            for (int m = 1; m < 16; m <<= 1) s += __shfl_xor(s, m, 64);
            lrow[r] = lrow[r] * corr[r] + s;
        }
        #pragma unroll
        for (int nd = 0; nd < 8; ++nd)
            #pragma unroll
            for (int r = 0; r < 4; ++r) oacc[nd][r] *= corr[r];

        // P -> per-wave LDS (re-layout to A-fragment), then PV
        char* pw = Pl[w];
        #pragma unroll
        for (int ni = 0; ni < 4; ++ni)
            #pragma unroll
            for (int r = 0; r < 4; ++r) {
                const int q = ((l >> 4) << 2) + r;
                const int t = (l & 15) + (ni << 4);
                *(ushort*)(pw + q * 128 + ((t * 2) ^ swz7(q))) = pb[ni][r];
            }
        #pragma unroll
        for (int tg = 0; tg < 2; ++tg) {
            const int q = l & 15;
            bf16x8 pf = *(const bf16x8*)(pw + q * 128 + ((((tg << 2) + (l >> 4)) << 4) ^ swz7(q)));
            #pragma unroll
            for (int nd = 0; nd < 8; ++nd) {
                const int d = (l & 15) + (nd << 4);
                bf16x8 vf = *(const bf16x8*)(Vt + d * 128 + ((((tg << 2) + (l >> 4)) << 4) ^ swz7(d)));
                oacc[nd] = __builtin_amdgcn_mfma_f32_16x16x32_bf16(pf, vf, oacc[nd], 0, 0, 0);
            }
        }
    }

    // epilogue: O /= l  (+ qv), bf16 store
    const size_t orow = qrow0 + ((l >> 4) << 2);
    #pragma unroll
    for (int r = 0; r < 4; ++r) {
        const float inv = 1.f / lrow[r];
        #pragma unroll
        for (int nd = 0; nd < 8; ++nd) {
            const size_t c = (l & 15) + (nd << 4);
            float v = oacc[nd][r] * inv;
            if (ADD_QV) v += bf2f(QV[bi + (orow + r) * ld + c]);
            O[bo + (orow + r) * 1024 + c] = f2bf(v);
        }
    }
}

// ---------------------------------------------------------------------------
// LayerNorm over (S,E) per batch on bf16 h1.
// ---------------------------------------------------------------------------
__global__ void ln_partial(const ushort* __restrict__ h1, float2* __restrict__ part)
{
    __shared__ float sa[8];
    const size_t off = ((size_t)blockIdx.x) << 15;
    float s = 0.f, s2 = 0.f;
    for (int i = threadIdx.x; i < 4096; i += 256) {
        uint4 u = *(const uint4*)(h1 + off + (size_t)i * 8);
        const ushort* e = (const ushort*)&u;
        #pragma unroll
        for (int j = 0; j < 8; ++j) { const float v = bf2f(e[j]); s += v; s2 += v * v; }
    }
    #pragma unroll
    for (int m = 1; m < 64; m <<= 1) { s += __shfl_xor(s, m, 64); s2 += __shfl_xor(s2, m, 64); }
    const int w = threadIdx.x >> 6;
    if ((threadIdx.x & 63) == 0) { sa[w * 2] = s; sa[w * 2 + 1] = s2; }
    __syncthreads();
    if (threadIdx.x == 0)
        part[blockIdx.x] = make_float2(sa[0] + sa[2] + sa[4] + sa[6], sa[1] + sa[3] + sa[5] + sa[7]);
}

__global__ void ln_finish(const float2* __restrict__ part, float2* __restrict__ stats)
{
    const int b = threadIdx.x;
    if (b < 8) {
        float s = 0.f, s2 = 0.f;
        for (int c = 0; c < 32; ++c) { const float2 v = part[b * 32 + c]; s += v.x; s2 += v.y; }
        const float mu = s * (1.f / 1048576.f);
        const float var = s2 * (1.f / 1048576.f) - mu * mu;
        stats[b] = make_float2(mu, rsqrtf(var + 1e-5f));
    }
}

__global__ void ln_apply(const ushort* __restrict__ h1, const float2* __restrict__ stats,
                         const float* __restrict__ gw, const float* __restrict__ gb,
                         ushort* __restrict__ hn)
{
    const size_t i = ((size_t)blockIdx.x * 256 + threadIdx.x) * 8;
    const int b = (int)(i >> 20);
    const size_t r = i & 1048575;
    const float2 st = stats[b];
    uint4 uv = *(const uint4*)(h1 + i);
    const float4 w0 = *(const float4*)(gw + r);
    const float4 w1 = *(const float4*)(gw + r + 4);
    const float4 b0 = *(const float4*)(gb + r);
    const float4 b1 = *(const float4*)(gb + r + 4);
    const float wv[8] = {w0.x, w0.y, w0.z, w0.w, w1.x, w1.y, w1.z, w1.w};
    const float bv[8] = {b0.x, b0.y, b0.z, b0.w, b1.x, b1.y, b1.z, b1.w};
    const ushort* ev = (const ushort*)&uv;
    ushort o[8];
    #pragma unroll
    for (int j = 0; j < 8; ++j)
        o[j] = f2bf((bf2f(ev[j]) - st.x) * st.y * wv[j] + bv[j]);
    *(uint4*)(hn + i) = *(const uint4*)o;
}

// ---------------------------------------------------------------------------
extern "C" void kernel_launch(void* const* d_in, const int* in_sizes, int n_in,
                              void* d_out, int out_size, void* d_ws, size_t ws_size,
                              hipStream_t stream)
{
    (void)in_sizes; (void)n_in; (void)out_size; (void)ws_size;
    auto P = [&](int i) { return (const float*)d_in[i]; };

    const size_t MB = 1u << 20;
    char* ws = (char*)d_ws;
    ushort* WB = (ushort*)ws;                       // 32 MB packed bf16 weights
    ushort* R0 = (ushort*)(ws + 32 * MB);           // 32 MB (48 MB during SA)
    ushort* R1 = (ushort*)(ws + 64 * MB);           // 32 MB (unused during SA)
    ushort* A0 = (ushort*)(ws + 96 * MB);           // 16 MB
    ushort* A1 = (ushort*)(ws + 112 * MB);          // 16 MB
    float*  BP = (float*)(ws + 128 * MB);           // 64 KB packed fp32 biases
    float2* PART = (float2*)(ws + 128 * MB + 65536);
    float2* STATS = PART + 256;

    PtrTab tab;
    const int wsrc[16] = {2,4,6,8,10,14,16,18,20,22,24,26,28,30,32,34};
    for (int i = 0; i < 16; ++i) { tab.w[i] = P(wsrc[i]); tab.b[i] = P(wsrc[i] + 1); }
    tab.x = P(0); tab.y = P(1);

    const dim3 blk(256);
    const float SA_SCALE = 0.08838834764831845f;    // 1/sqrt(128)
    auto Wp = [&](int w) { return WB + (size_t)w * 1048576; };
    auto Bp = [&](int w) { return BP + (size_t)w * 1024; };

    cvt_pack<<<dim3(16392), blk, 0, stream>>>(tab, WB, A0, A1, BP);

    // --- cross attention ---
    gemm_bf16<0,0,ushort,ushort><<<dim3(1024), blk, 0, stream>>>(A0, Wp(0), Bp(0), (const ushort*)nullptr, R0, 2048); // q|qv
    gemm_bf16<0,0,ushort,ushort><<<dim3(1024), blk, 0, stream>>>(A1, Wp(2), Bp(2), (const ushort*)nullptr, R1, 2048); // k|kv
    attn_fwd<1><<<dim3(1024), blk, 0, stream>>>(R0, R1, R1 + 1024, R0 + 1024, A0, 2048, 1.0f);
    gemm_bf16<0,1,float,ushort><<<dim3(512), blk, 0, stream>>>(A0, Wp(4), Bp(4), P(0), A1, 1024);                     // h1 = x + o(ca)

    // --- LayerNorm over (S,E) per batch ---
    ln_partial<<<dim3(256), blk, 0, stream>>>(A1, PART);
    ln_finish<<<dim3(1), dim3(64), 0, stream>>>(PART, STATS);
    ln_apply<<<dim3(4096), blk, 0, stream>>>(A1, STATS, P(12), P(13), A0);                                            // hn

    // --- FeedForward ---
    gemm_bf16<1,0,ushort,ushort><<<dim3(512), blk, 0, stream>>>(A0, Wp(5), Bp(5), (const ushort*)nullptr, R0, 1024);  // f1
    gemm_bf16<1,0,ushort,ushort><<<dim3(512), blk, 0, stream>>>(R0, Wp(6), Bp(6), (const ushort*)nullptr, R1, 1024);  // f2
    gemm_bf16<1,1,ushort,ushort><<<dim3(512), blk, 0, stream>>>(R1, Wp(7), Bp(7), A0, A1, 1024);                      // h2 = hn + lr(f3)

    // --- self attention 1 ---
    gemm_bf16<0,0,ushort,ushort><<<dim3(1536), blk, 0, stream>>>(A1, Wp(8), Bp(8), (const ushort*)nullptr, R0, 3072); // q|k|v
    attn_fwd<0><<<dim3(1024), blk, 0, stream>>>(R0, R0 + 1024, R0 + 2048, nullptr, A0, 3072, SA_SCALE);
    gemm_bf16<0,0,ushort,ushort><<<dim3(512), blk, 0, stream>>>(A0, Wp(11), Bp(11), (const ushort*)nullptr, A1, 1024);// h3

    // --- self attention 2 ---
    gemm_bf16<0,0,ushort,ushort><<<dim3(1536), blk, 0, stream>>>(A1, Wp(12), Bp(12), (const ushort*)nullptr, R0, 3072);
    attn_fwd<0><<<dim3(1024), blk, 0, stream>>>(R0, R0 + 1024, R0 + 2048, nullptr, A0, 3072, SA_SCALE);
    gemm_bf16<0,0,ushort,float><<<dim3(512), blk, 0, stream>>>(A0, Wp(15), Bp(15), (const ushort*)nullptr, (float*)d_out, 1024);
}